// Round 1
// baseline (189.294 us; speedup 1.0000x reference)
//
#include <hip/hip_runtime.h>

#define HN 32
#define MM 16
#define DD 128
#define NN 4096
#define PP 8192
#define CHUNK 512
#define NCH 17          // 16 cache chunks + 1 new-token chunk
#define TP 64

// ws layout (floats)
#define QKV_SZ  (3*HN*MM*DD)            // 196608 : q,k,v as [h][m][d]
#define PMU_OFF QKV_SZ
#define PMU_SZ  (HN*NCH*MM)             // 8704
#define PS_OFF  (PMU_OFF + PMU_SZ)
#define PACC_OFF (PS_OFF + PMU_SZ)
#define PACC_SZ (HN*NCH*MM*DD)          // 1114112

// ---------------- Kernel 1: QKV projection (atomic accumulate) ----------------
// grid = 768 : mat(3) x coltile(8 x 512) x rowchunk(32 x 128)
__global__ __launch_bounds__(256) void qkv_kernel(
    const float* __restrict__ X, const float* __restrict__ Wq,
    const float* __restrict__ Wk, const float* __restrict__ Wv,
    float* __restrict__ qkv)
{
    __shared__ float Xs[MM][128];
    const int bx  = blockIdx.x;
    const int mat = bx >> 8;          // 256 blocks per matrix
    const int r   = bx & 255;
    const int ct  = r >> 5;           // 0..7
    const int rc  = r & 31;           // 0..31
    const int col0 = ct << 9;
    const int i0   = rc << 7;
    const float* W = (mat == 0) ? Wq : (mat == 1) ? Wk : Wv;
    const int t = threadIdx.x;

    for (int f = t; f < MM*128; f += 256)
        Xs[f >> 7][f & 127] = X[(f >> 7)*NN + i0 + (f & 127)];
    __syncthreads();

    const int c0 = col0 + t, c1 = col0 + 256 + t;
    float a0[MM], a1[MM];
#pragma unroll
    for (int m = 0; m < MM; ++m) { a0[m] = 0.f; a1[m] = 0.f; }

    for (int i4 = 0; i4 < 128; i4 += 4) {
        const float* Wr = W + (size_t)(i0 + i4) * NN;
        float w00 = Wr[c0],        w01 = Wr[c1];
        float w10 = Wr[NN + c0],   w11 = Wr[NN + c1];
        float w20 = Wr[2*NN + c0], w21 = Wr[2*NN + c1];
        float w30 = Wr[3*NN + c0], w31 = Wr[3*NN + c1];
#pragma unroll
        for (int m = 0; m < MM; ++m) {
            float4 x = *reinterpret_cast<const float4*>(&Xs[m][i4]);
            a0[m] += x.x*w00 + x.y*w10 + x.z*w20 + x.w*w30;
            a1[m] += x.x*w01 + x.y*w11 + x.z*w21 + x.w*w31;
        }
    }
    float* base = qkv + (size_t)mat * HN*MM*DD;
    const int h0 = c0 >> 7, d0 = c0 & 127;
    const int h1 = c1 >> 7, d1 = c1 & 127;
#pragma unroll
    for (int m = 0; m < MM; ++m) {
        atomicAdd(&base[(h0*MM + m)*DD + d0], a0[m]);
        atomicAdd(&base[(h1*MM + m)*DD + d1], a1[m]);
    }
}

// ---------------- Kernel 2: flash-decode partials ----------------
// grid = (NCH, HN), block 256
__global__ __launch_bounds__(256) void attn_partial_kernel(
    const float* __restrict__ cacheK, const float* __restrict__ cacheV,
    const float* __restrict__ qkv, float* __restrict__ pmu,
    float* __restrict__ ps, float* __restrict__ pacc)
{
    __shared__ float Qs[MM][DD];                    // 8 KB
    __shared__ float KV[TP][DD + 4];                // 33 KB (padded: breaks bank conflicts)
    __shared__ __align__(16) float Ws_[TP][MM];     // 4 KB, scores then weights, [p][m]
    __shared__ __align__(16) float mu_s[MM];
    __shared__ __align__(16) float s_s[MM];
    __shared__ __align__(16) float r_s[MM];

    const int chunk = blockIdx.x;
    const int h     = blockIdx.y;
    const int t     = threadIdx.x;

    const float* q_ws = qkv;
    const float* k_ws = qkv + HN*MM*DD;
    const float* v_ws = qkv + 2*HN*MM*DD;

    for (int f = t; f < MM*DD/4; f += 256) {
        int m = f >> 5, c4 = f & 31;
        reinterpret_cast<float4*>(&Qs[m][0])[c4] =
            reinterpret_cast<const float4*>(q_ws + (size_t)(h*MM + m)*DD)[c4];
    }
    if (t < MM) { mu_s[t] = -3.0e38f; s_s[t] = 0.0f; }

    float acc[4][8];
#pragma unroll
    for (int q = 0; q < 4; ++q)
#pragma unroll
        for (int k = 0; k < 8; ++k) acc[q][k] = 0.0f;

    const int cnt   = (chunk < 16) ? CHUNK : MM;
    const int ntile = (cnt + TP - 1) / TP;

    const int pg = t & 31, mg = t >> 5;                       // score role
    const int psi = t >> 6, mgv = (t >> 4) & 3, g = t & 15;   // V role

    for (int tt = 0; tt < ntile; ++tt) {
        const int t0 = tt * TP;
        const int valid = min(TP, cnt - t0);

        __syncthreads();
        // stage K tile
        for (int f = t; f < TP*DD/4; f += 256) {
            int row = f >> 5, c4 = f & 31;
            float4 v = make_float4(0.f, 0.f, 0.f, 0.f);
            if (row < valid) {
                const float* kp = (chunk < 16)
                    ? cacheK + ((size_t)h*PP + chunk*CHUNK + t0 + row)*DD
                    : k_ws + (size_t)(h*MM + t0 + row)*DD;
                v = reinterpret_cast<const float4*>(kp)[c4];
            }
            *reinterpret_cast<float4*>(&KV[row][c4*4]) = v;
        }
        __syncthreads();
        // scores: each thread 2p x 2m
        {
            const int p0 = pg, p1 = pg + 32;
            const int m0 = mg, m1 = mg + 8;
            float s00 = 0, s01 = 0, s10 = 0, s11 = 0;
#pragma unroll 4
            for (int dq = 0; dq < DD/4; ++dq) {
                float4 k0 = *reinterpret_cast<const float4*>(&KV[p0][dq*4]);
                float4 k1 = *reinterpret_cast<const float4*>(&KV[p1][dq*4]);
                float4 q0 = *reinterpret_cast<const float4*>(&Qs[m0][dq*4]);
                float4 q1 = *reinterpret_cast<const float4*>(&Qs[m1][dq*4]);
                s00 += q0.x*k0.x + q0.y*k0.y + q0.z*k0.z + q0.w*k0.w;
                s01 += q0.x*k1.x + q0.y*k1.y + q0.z*k1.z + q0.w*k1.w;
                s10 += q1.x*k0.x + q1.y*k0.y + q1.z*k0.z + q1.w*k0.w;
                s11 += q1.x*k1.x + q1.y*k1.y + q1.z*k1.z + q1.w*k1.w;
            }
            Ws_[p0][m0] = s00;
            Ws_[p1][m0] = s01;
            Ws_[p0][m1] = s10;
            Ws_[p1][m1] = s11;
        }
        __syncthreads();
        // stage V tile (overwrites KV; scores already consumed K)
        for (int f = t; f < TP*DD/4; f += 256) {
            int row = f >> 5, c4 = f & 31;
            float4 v = make_float4(0.f, 0.f, 0.f, 0.f);
            if (row < valid) {
                const float* vp = (chunk < 16)
                    ? cacheV + ((size_t)h*PP + chunk*CHUNK + t0 + row)*DD
                    : v_ws + (size_t)(h*MM + t0 + row)*DD;
                v = reinterpret_cast<const float4*>(vp)[c4];
            }
            *reinterpret_cast<float4*>(&KV[row][c4*4]) = v;
        }
        // online softmax update (threads 0..127; overlaps with V stage issue)
        if (t < 128) {
            const int m = t >> 3, j = t & 7;
            float mx = -3.0e38f;
            for (int p = j; p < TP; p += 8)
                if (p < valid) mx = fmaxf(mx, Ws_[p][m]);
            mx = fmaxf(mx, __shfl_xor(mx, 1));
            mx = fmaxf(mx, __shfl_xor(mx, 2));
            mx = fmaxf(mx, __shfl_xor(mx, 4));
            float mu_old = mu_s[m];
            float mu_new = fmaxf(mu_old, mx);
            float sum = 0.f;
            for (int p = j; p < TP; p += 8) {
                float w = 0.f;
                if (p < valid) w = __expf(Ws_[p][m] - mu_new);
                Ws_[p][m] = w;
                sum += w;
            }
            sum += __shfl_xor(sum, 1);
            sum += __shfl_xor(sum, 2);
            sum += __shfl_xor(sum, 4);
            if (j == 0) {
                float rr = __expf(mu_old - mu_new);
                r_s[m] = rr;
                mu_s[m] = mu_new;
                s_s[m] = s_s[m] * rr + sum;
            }
        }
        __syncthreads();
        // accumulate P·V: thread (psi, mgv, g) -> m in {4mgv..4mgv+3}, d in [8g, 8g+8)
        {
            float4 rr4 = *reinterpret_cast<const float4*>(&r_s[mgv*4]);
#pragma unroll
            for (int q = 0; q < 4; ++q) {
                float rq = (&rr4.x)[q];
#pragma unroll
                for (int k = 0; k < 8; ++k) acc[q][k] *= rq;
            }
#pragma unroll 2
            for (int p = psi; p < TP; p += 4) {
                float4 w4 = *reinterpret_cast<const float4*>(&Ws_[p][mgv*4]);
                float4 v0 = *reinterpret_cast<const float4*>(&KV[p][g*8]);
                float4 v1 = *reinterpret_cast<const float4*>(&KV[p][g*8 + 4]);
#pragma unroll
                for (int q = 0; q < 4; ++q) {
                    float wq = (&w4.x)[q];
                    acc[q][0] += wq*v0.x; acc[q][1] += wq*v0.y;
                    acc[q][2] += wq*v0.z; acc[q][3] += wq*v0.w;
                    acc[q][4] += wq*v1.x; acc[q][5] += wq*v1.y;
                    acc[q][6] += wq*v1.z; acc[q][7] += wq*v1.w;
                }
            }
        }
    }

    // reduce the 4 psi-partials into Qs (reused as scratch) and write out
    for (int s = 0; s < 4; ++s) {
        __syncthreads();
        if (psi == s) {
#pragma unroll
            for (int q = 0; q < 4; ++q) {
                int m = mgv*4 + q;
#pragma unroll
                for (int k = 0; k < 8; ++k) {
                    if (s == 0) Qs[m][g*8 + k] = acc[q][k];
                    else        Qs[m][g*8 + k] += acc[q][k];
                }
            }
        }
    }
    __syncthreads();
    float* pa = pacc + (size_t)(h*NCH + chunk)*MM*DD;
    for (int f = t; f < MM*DD; f += 256) pa[f] = Qs[f >> 7][f & 127];
    if (t < MM) {
        pmu[(h*NCH + chunk)*MM + t] = mu_s[t];
        ps [(h*NCH + chunk)*MM + t] = s_s[t];
    }
}

// ---------------- Kernel 3: combine partials ----------------
__global__ __launch_bounds__(128) void combine_kernel(
    const float* __restrict__ pmu, const float* __restrict__ ps,
    const float* __restrict__ pacc, float* __restrict__ out)
{
    const int b = blockIdx.x;          // h*16 + m
    const int h = b >> 4, m = b & 15;
    const int d = threadIdx.x;
    float mu[NCH];
    float gm = -3.0e38f;
#pragma unroll
    for (int c = 0; c < NCH; ++c) {
        mu[c] = pmu[(h*NCH + c)*MM + m];
        gm = fmaxf(gm, mu[c]);
    }
    float stot = 0.f, a = 0.f;
#pragma unroll
    for (int c = 0; c < NCH; ++c) {
        float f = __expf(mu[c] - gm);
        stot += ps[(h*NCH + c)*MM + m] * f;
        a += pacc[((size_t)(h*NCH + c)*MM + m)*DD + d] * f;
    }
    out[m*NN + h*DD + d] = a / stot;
}

extern "C" void kernel_launch(void* const* d_in, const int* in_sizes, int n_in,
                              void* d_out, int out_size, void* d_ws, size_t ws_size,
                              hipStream_t stream) {
    const float* X  = (const float*)d_in[0];
    const float* Wq = (const float*)d_in[1];
    const float* Wk = (const float*)d_in[2];
    const float* Wv = (const float*)d_in[3];
    const float* cK = (const float*)d_in[4];
    const float* cV = (const float*)d_in[5];
    float* out = (float*)d_out;

    float* ws    = (float*)d_ws;
    float* qkv   = ws;
    float* pmu_p = ws + PMU_OFF;
    float* ps_p  = ws + PS_OFF;
    float* pacc_p = ws + PACC_OFF;

    hipMemsetAsync(qkv, 0, (size_t)QKV_SZ * sizeof(float), stream);
    qkv_kernel<<<768, 256, 0, stream>>>(X, Wq, Wk, Wv, qkv);
    attn_partial_kernel<<<dim3(NCH, HN), 256, 0, stream>>>(cK, cV, qkv, pmu_p, ps_p, pacc_p);
    combine_kernel<<<HN*MM, 128, 0, stream>>>(pmu_p, ps_p, pacc_p, out);
}